// Round 1
// baseline (252.211 us; speedup 1.0000x reference)
//
#include <hip/hip_runtime.h>
#include <hip/hip_bf16.h>

#define B_ROWS 4096
#define D_DIM  512
#define N_ROWS 8192   // 2B
#define BM 128
#define BN 128
#define BK 64

typedef __bf16 bf16x8 __attribute__((ext_vector_type(8)));
typedef float  f32x4  __attribute__((ext_vector_type(4)));

// ---------------------------------------------------------------------------
// Kernel 1: per-pair prep. Block r handles polyline row r and c row r.
// Computes norms (fp32), pos[r] = cos sim of the pair (fp32, exact),
// writes normalized bf16 rows into Z[r] and Z[r+B], zeroes row_sum.
// ---------------------------------------------------------------------------
__global__ __launch_bounds__(256) void prep_kernel(
    const float* __restrict__ poly, const float* __restrict__ cemb,
    __bf16* __restrict__ Z, float* __restrict__ row_sum,
    float* __restrict__ pos)
{
    const int r = blockIdx.x;
    const int t = threadIdx.x;
    const float* prow = poly + (size_t)r * D_DIM;
    const float* crow = cemb + (size_t)r * D_DIM;

    float p0 = prow[t], p1 = prow[t + 256];
    float c0 = crow[t], c1 = crow[t + 256];

    float ssp = p0 * p0 + p1 * p1;
    float ssc = c0 * c0 + c1 * c1;
    float dt  = p0 * c0 + p1 * c1;

    #pragma unroll
    for (int m = 1; m < 64; m <<= 1) {
        ssp += __shfl_xor(ssp, m);
        ssc += __shfl_xor(ssc, m);
        dt  += __shfl_xor(dt,  m);
    }
    __shared__ float red[3][4];
    const int wave = t >> 6;
    if ((t & 63) == 0) { red[0][wave] = ssp; red[1][wave] = ssc; red[2][wave] = dt; }
    __syncthreads();
    ssp = red[0][0] + red[0][1] + red[0][2] + red[0][3];
    ssc = red[1][0] + red[1][1] + red[1][2] + red[1][3];
    dt  = red[2][0] + red[2][1] + red[2][2] + red[2][3];

    const float sp = 1.0f / fmaxf(sqrtf(ssp), 1e-12f);
    const float sc = 1.0f / fmaxf(sqrtf(ssc), 1e-12f);

    __bf16* zp = Z + (size_t)r * D_DIM;
    __bf16* zc = Z + (size_t)(r + B_ROWS) * D_DIM;
    zp[t]       = (__bf16)(p0 * sp);
    zp[t + 256] = (__bf16)(p1 * sp);
    zc[t]       = (__bf16)(c0 * sc);
    zc[t + 256] = (__bf16)(c1 * sc);

    if (t == 0) {
        pos[r] = dt * sp * sc;
        row_sum[2 * r]     = 0.0f;
        row_sum[2 * r + 1] = 0.0f;
    }
}

// ---------------------------------------------------------------------------
// Kernel 2: sim = Z Z^T in 128x128 tiles; exp(sim/T) row-summed into row_sum.
// 4 waves (2x2), each wave 64x64 = 4x4 tiles of mfma_f32_16x16x32_bf16.
// Staging via global_load_lds width 16 (wave-uniform base + lane*16).
// ---------------------------------------------------------------------------
__global__ __launch_bounds__(256) void sim_kernel(
    const __bf16* __restrict__ Z, float* __restrict__ row_sum)
{
    __shared__ __align__(16) __bf16 As[BM * BK];
    __shared__ __align__(16) __bf16 Bs[BN * BK];

    const int ibase = blockIdx.y * BM;
    const int jbase = blockIdx.x * BN;
    const int tid   = threadIdx.x;

    const int srow = tid >> 3;        // staging row within 32-row group
    const int scol = (tid & 7) * 8;   // staging col (bf16 elems)

    const int wave = tid >> 6;
    const int lane = tid & 63;
    const int wi = (wave >> 1) * 64;  // wave row offset in 128-tile
    const int wj = (wave & 1) * 64;   // wave col offset
    const int quad = lane >> 4;
    const int c    = lane & 15;

    f32x4 acc[4][4] = {};

    for (int k0 = 0; k0 < D_DIM; k0 += BK) {
        // stage A tile (128 x 64 bf16, row-major, unpadded) and B tile
        #pragma unroll
        for (int it = 0; it < 4; ++it) {
            const int row = it * 32 + srow;
            const __bf16* ga = Z + (size_t)(ibase + row) * D_DIM + k0 + scol;
            const __bf16* gb = Z + (size_t)(jbase + row) * D_DIM + k0 + scol;
            __builtin_amdgcn_global_load_lds(
                (const __attribute__((address_space(1))) void*)ga,
                (__attribute__((address_space(3))) void*)(As + it * 2048 + tid * 8),
                16, 0, 0);
            __builtin_amdgcn_global_load_lds(
                (const __attribute__((address_space(1))) void*)gb,
                (__attribute__((address_space(3))) void*)(Bs + it * 2048 + tid * 8),
                16, 0, 0);
        }
        __syncthreads();

        #pragma unroll
        for (int kk = 0; kk < BK; kk += 32) {
            bf16x8 a[4], b[4];
            #pragma unroll
            for (int ti = 0; ti < 4; ++ti)
                a[ti] = *(const bf16x8*)&As[(wi + ti * 16 + c) * BK + kk + quad * 8];
            #pragma unroll
            for (int tj = 0; tj < 4; ++tj)
                b[tj] = *(const bf16x8*)&Bs[(wj + tj * 16 + c) * BK + kk + quad * 8];
            #pragma unroll
            for (int ti = 0; ti < 4; ++ti)
                #pragma unroll
                for (int tj = 0; tj < 4; ++tj)
                    acc[ti][tj] = __builtin_amdgcn_mfma_f32_16x16x32_bf16(
                        a[ti], b[tj], acc[ti][tj], 0, 0, 0);
        }
        __syncthreads();
    }

    // Epilogue: v = sum_j exp(sim/T); exp(x/0.5) = exp2(2*log2(e)*x)
    const float K2 = 2.885390081777927f;
    #pragma unroll
    for (int ti = 0; ti < 4; ++ti) {
        #pragma unroll
        for (int r = 0; r < 4; ++r) {
            float v = 0.0f;
            #pragma unroll
            for (int tj = 0; tj < 4; ++tj)
                v += exp2f(K2 * acc[ti][tj][r]);
            // reduce over the 16 columns held by lanes sharing this quad
            v += __shfl_xor(v, 1);
            v += __shfl_xor(v, 2);
            v += __shfl_xor(v, 4);
            v += __shfl_xor(v, 8);
            if (c == 0)
                atomicAdd(&row_sum[ibase + wi + ti * 16 + quad * 4 + r], v);
        }
    }
}

// ---------------------------------------------------------------------------
// Kernel 3: loss = (sum_i log(row_sum[i] - e^2) - 4 * sum_r pos[r]) / 8192
//   (each pair's positive appears twice; 1/T = 2 -> factor 4)
// ---------------------------------------------------------------------------
__global__ __launch_bounds__(256) void finalize_kernel(
    const float* __restrict__ row_sum, const float* __restrict__ pos,
    float* __restrict__ out)
{
    const float E2 = 7.38905609893065f;  // exp(1/T), the masked diagonal term
    const int t = threadIdx.x;
    float accL = 0.0f, accP = 0.0f;
    for (int i = t; i < N_ROWS; i += 256)
        accL += logf(row_sum[i] - E2);
    for (int r = t; r < B_ROWS; r += 256)
        accP += pos[r];
    #pragma unroll
    for (int m = 1; m < 64; m <<= 1) {
        accL += __shfl_xor(accL, m);
        accP += __shfl_xor(accP, m);
    }
    __shared__ float red[2][4];
    const int wave = t >> 6;
    if ((t & 63) == 0) { red[0][wave] = accL; red[1][wave] = accP; }
    __syncthreads();
    if (t == 0) {
        const float L = red[0][0] + red[0][1] + red[0][2] + red[0][3];
        const float P = red[1][0] + red[1][1] + red[1][2] + red[1][3];
        out[0] = (L - 4.0f * P) / (float)N_ROWS;
    }
}

extern "C" void kernel_launch(void* const* d_in, const int* in_sizes, int n_in,
                              void* d_out, int out_size, void* d_ws, size_t ws_size,
                              hipStream_t stream) {
    const float* poly = (const float*)d_in[0];
    const float* cemb = (const float*)d_in[1];

    __bf16* Z       = (__bf16*)d_ws;
    float*  row_sum = (float*)((char*)d_ws + (size_t)N_ROWS * D_DIM * sizeof(__bf16));
    float*  pos     = row_sum + N_ROWS;
    float*  out     = (float*)d_out;

    prep_kernel<<<B_ROWS, 256, 0, stream>>>(poly, cemb, Z, row_sum, pos);
    dim3 grid(N_ROWS / BN, N_ROWS / BM);
    sim_kernel<<<grid, 256, 0, stream>>>(Z, row_sum);
    finalize_kernel<<<1, 256, 0, stream>>>(row_sum, pos, out);
}

// Round 2
// 160.592 us; speedup vs baseline: 1.5705x; 1.5705x over previous
//
#include <hip/hip_runtime.h>
#include <hip/hip_bf16.h>

#define B_ROWS 4096
#define D_DIM  512
#define N_ROWS 8192   // 2B
#define BM 128
#define BN 128
#define BK 64
#define NBLK (N_ROWS / BM)          // 64 row-blocks
#define NPAIR (NBLK * (NBLK + 1) / 2)  // 2080 upper-tri block pairs

typedef __bf16 bf16x8 __attribute__((ext_vector_type(8)));
typedef float  f32x4  __attribute__((ext_vector_type(4)));

// ---------------------------------------------------------------------------
// Kernel 1: per-pair prep. Block r computes norms, pos[r] (fp32 exact),
// normalized bf16 rows Z[r], Z[r+B]; zeroes row_sum.
// ---------------------------------------------------------------------------
__global__ __launch_bounds__(256) void prep_kernel(
    const float* __restrict__ poly, const float* __restrict__ cemb,
    __bf16* __restrict__ Z, float* __restrict__ row_sum,
    float* __restrict__ pos)
{
    const int r = blockIdx.x;
    const int t = threadIdx.x;
    const float* prow = poly + (size_t)r * D_DIM;
    const float* crow = cemb + (size_t)r * D_DIM;

    float p0 = prow[t], p1 = prow[t + 256];
    float c0 = crow[t], c1 = crow[t + 256];

    float ssp = p0 * p0 + p1 * p1;
    float ssc = c0 * c0 + c1 * c1;
    float dt  = p0 * c0 + p1 * c1;

    #pragma unroll
    for (int m = 1; m < 64; m <<= 1) {
        ssp += __shfl_xor(ssp, m);
        ssc += __shfl_xor(ssc, m);
        dt  += __shfl_xor(dt,  m);
    }
    __shared__ float red[3][4];
    const int wave = t >> 6;
    if ((t & 63) == 0) { red[0][wave] = ssp; red[1][wave] = ssc; red[2][wave] = dt; }
    __syncthreads();
    ssp = red[0][0] + red[0][1] + red[0][2] + red[0][3];
    ssc = red[1][0] + red[1][1] + red[1][2] + red[1][3];
    dt  = red[2][0] + red[2][1] + red[2][2] + red[2][3];

    const float sp = 1.0f / fmaxf(sqrtf(ssp), 1e-12f);
    const float sc = 1.0f / fmaxf(sqrtf(ssc), 1e-12f);

    __bf16* zp = Z + (size_t)r * D_DIM;
    __bf16* zc = Z + (size_t)(r + B_ROWS) * D_DIM;
    zp[t]       = (__bf16)(p0 * sp);
    zp[t + 256] = (__bf16)(p1 * sp);
    zc[t]       = (__bf16)(c0 * sc);
    zc[t + 256] = (__bf16)(c1 * sc);

    if (t == 0) {
        pos[r] = dt * sp * sc;
        row_sum[2 * r]     = 0.0f;
        row_sum[2 * r + 1] = 0.0f;
    }
}

// ---------------------------------------------------------------------------
// Kernel 2: symmetric sim = Z Z^T. Only upper-triangular 128x128 block pairs
// (bi <= bj). Off-diag blocks add exp(sim/T) to BOTH row sums (over cols)
// and col sums (over rows). Diagonal blocks: full tile, row sums only,
// B tile == A tile (no B staging).
// LDS XOR swizzle: row r's 16B chunk c lives at slot c ^ (r&7) -> 2-way
// conflicts only (free), vs 16-way unswizzled.
// ---------------------------------------------------------------------------
__global__ __launch_bounds__(256) void sim_kernel(
    const __bf16* __restrict__ Z, float* __restrict__ row_sum)
{
    __shared__ __align__(16) __bf16 As[BM * BK];
    __shared__ __align__(16) __bf16 Bs[BN * BK];

    // decode blockIdx.x -> (bi, bj), bi <= bj, via triangular numbering
    // C(b) = b*(129-b)/2 pairs before row-block b
    const int t0 = blockIdx.x;
    int bi = (int)((129.0f - sqrtf(16641.0f - 8.0f * (float)t0)) * 0.5f);
    #define CFN(b) ((b) * (129 - (b)) / 2)
    while (CFN(bi + 1) <= t0) ++bi;
    while (CFN(bi) > t0) --bi;
    const int bj = bi + (t0 - CFN(bi));
    #undef CFN
    const bool diag = (bi == bj);

    const int ibase = bi * BM;
    const int jbase = bj * BN;
    const int tid   = threadIdx.x;

    const int srow  = tid >> 3;              // staging row within 32-row group
    const int gchk  = (tid & 7) ^ (srow & 7);  // swizzled source chunk (16B units)

    const int wave = tid >> 6;
    const int lane = tid & 63;
    const int wi = (wave >> 1) * 64;
    const int wj = (wave & 1) * 64;
    const int quad = lane >> 4;
    const int c    = lane & 15;

    f32x4 acc[4][4] = {};

    for (int k0 = 0; k0 < D_DIM; k0 += BK) {
        #pragma unroll
        for (int it = 0; it < 4; ++it) {
            const int row = it * 32 + srow;
            const __bf16* ga = Z + (size_t)(ibase + row) * D_DIM + k0 + gchk * 8;
            __builtin_amdgcn_global_load_lds(
                (const __attribute__((address_space(1))) void*)ga,
                (__attribute__((address_space(3))) void*)(As + it * 2048 + tid * 8),
                16, 0, 0);
        }
        if (!diag) {
            #pragma unroll
            for (int it = 0; it < 4; ++it) {
                const int row = it * 32 + srow;
                const __bf16* gb = Z + (size_t)(jbase + row) * D_DIM + k0 + gchk * 8;
                __builtin_amdgcn_global_load_lds(
                    (const __attribute__((address_space(1))) void*)gb,
                    (__attribute__((address_space(3))) void*)(Bs + it * 2048 + tid * 8),
                    16, 0, 0);
            }
        }
        __syncthreads();

        const __bf16* bsrc = diag ? As : Bs;
        #pragma unroll
        for (int kk = 0; kk < BK; kk += 32) {
            const int sw = ((kk >> 3) + quad) ^ (c & 7);  // swizzled chunk for readers
            bf16x8 a[4], b[4];
            #pragma unroll
            for (int ti = 0; ti < 4; ++ti)
                a[ti] = *(const bf16x8*)&As[(wi + ti * 16 + c) * BK + sw * 8];
            #pragma unroll
            for (int tj = 0; tj < 4; ++tj)
                b[tj] = *(const bf16x8*)&bsrc[(wj + tj * 16 + c) * BK + sw * 8];
            #pragma unroll
            for (int ti = 0; ti < 4; ++ti)
                #pragma unroll
                for (int tj = 0; tj < 4; ++tj)
                    acc[ti][tj] = __builtin_amdgcn_mfma_f32_16x16x32_bf16(
                        a[ti], b[tj], acc[ti][tj], 0, 0, 0);
        }
        __syncthreads();
    }

    // Epilogue: e = exp(sim/T) = exp2(2*log2e * sim)
    const float K2 = 2.885390081777927f;
    if (diag) {
        #pragma unroll
        for (int ti = 0; ti < 4; ++ti) {
            #pragma unroll
            for (int r = 0; r < 4; ++r) {
                float v = 0.0f;
                #pragma unroll
                for (int tj = 0; tj < 4; ++tj)
                    v += exp2f(K2 * acc[ti][tj][r]);
                v += __shfl_xor(v, 1);
                v += __shfl_xor(v, 2);
                v += __shfl_xor(v, 4);
                v += __shfl_xor(v, 8);
                if (c == 0)
                    atomicAdd(&row_sum[ibase + wi + ti * 16 + quad * 4 + r], v);
            }
        }
    } else {
        float colacc[4] = {0.0f, 0.0f, 0.0f, 0.0f};
        #pragma unroll
        for (int ti = 0; ti < 4; ++ti) {
            #pragma unroll
            for (int r = 0; r < 4; ++r) {
                float v = 0.0f;
                #pragma unroll
                for (int tj = 0; tj < 4; ++tj) {
                    const float e = exp2f(K2 * acc[ti][tj][r]);
                    v += e;
                    colacc[tj] += e;
                }
                v += __shfl_xor(v, 1);
                v += __shfl_xor(v, 2);
                v += __shfl_xor(v, 4);
                v += __shfl_xor(v, 8);
                if (c == 0)
                    atomicAdd(&row_sum[ibase + wi + ti * 16 + quad * 4 + r], v);
            }
        }
        #pragma unroll
        for (int tj = 0; tj < 4; ++tj) {
            float w = colacc[tj];
            w += __shfl_xor(w, 16);
            w += __shfl_xor(w, 32);
            if (quad == 0)
                atomicAdd(&row_sum[jbase + wj + tj * 16 + c], w);
        }
    }
}

// ---------------------------------------------------------------------------
// Kernel 3: loss = (sum_i log(row_sum[i] - e^2) - 4 * sum_r pos[r]) / 8192
// ---------------------------------------------------------------------------
__global__ __launch_bounds__(256) void finalize_kernel(
    const float* __restrict__ row_sum, const float* __restrict__ pos,
    float* __restrict__ out)
{
    const float E2 = 7.38905609893065f;  // exp(1/T): masked diagonal term
    const int t = threadIdx.x;
    float accL = 0.0f, accP = 0.0f;
    for (int i = t; i < N_ROWS; i += 256)
        accL += __logf(row_sum[i] - E2);
    for (int r = t; r < B_ROWS; r += 256)
        accP += pos[r];
    #pragma unroll
    for (int m = 1; m < 64; m <<= 1) {
        accL += __shfl_xor(accL, m);
        accP += __shfl_xor(accP, m);
    }
    __shared__ float red[2][4];
    const int wave = t >> 6;
    if ((t & 63) == 0) { red[0][wave] = accL; red[1][wave] = accP; }
    __syncthreads();
    if (t == 0) {
        const float L = red[0][0] + red[0][1] + red[0][2] + red[0][3];
        const float P = red[1][0] + red[1][1] + red[1][2] + red[1][3];
        out[0] = (L - 4.0f * P) / (float)N_ROWS;
    }
}

extern "C" void kernel_launch(void* const* d_in, const int* in_sizes, int n_in,
                              void* d_out, int out_size, void* d_ws, size_t ws_size,
                              hipStream_t stream) {
    const float* poly = (const float*)d_in[0];
    const float* cemb = (const float*)d_in[1];

    __bf16* Z       = (__bf16*)d_ws;
    float*  row_sum = (float*)((char*)d_ws + (size_t)N_ROWS * D_DIM * sizeof(__bf16));
    float*  pos     = row_sum + N_ROWS;
    float*  out     = (float*)d_out;

    prep_kernel<<<B_ROWS, 256, 0, stream>>>(poly, cemb, Z, row_sum, pos);
    sim_kernel<<<NPAIR, 256, 0, stream>>>(Z, row_sum);
    finalize_kernel<<<1, 256, 0, stream>>>(row_sum, pos, out);
}